// Round 6
// baseline (922.274 us; speedup 1.0000x reference)
//
#include <hip/hip_runtime.h>

// 2-layer GRU (reset_after, sigmoid gates, linear act, no bias) + Wout.
// B=16384, T=25, D=128. 256 blocks x 1024 threads (16 waves); block owns 64
// batch rows. Waves 0-7 = layer1 @ step it, waves 8-15 = layer2 @ step it-1.
// FLIPPED MFMA operands: weights are the A operand (24 frags = 96 regs,
// pinned to AGPRs via asm "+a"; amdgpu_waves_per_eu(4,4) fixes the budget at
// 128/wave — rounds 2/5 proved the allocator otherwise scratch-spills them).
// Data (x_t / h) is the B operand, streamed from LDS as ds_read_b128.
// C/D layout => D[gate-col][batch]: h-writes are 1 ds_write_b64 and h_prev
// re-reads 1 ds_read_b64 per n-tile. x is DMA'd f32 -> LDS, converted once
// per iter to f16 by all waves (P1), then consumed by layer-1 waves (P2).

typedef _Float16 half8 __attribute__((ext_vector_type(8)));
typedef __fp16  fp16x2 __attribute__((ext_vector_type(2)));
typedef __fp16  fp16x4 __attribute__((ext_vector_type(4)));
typedef float    f32x4 __attribute__((ext_vector_type(4)));

#define MFMA(a, b, c) __builtin_amdgcn_mfma_f32_16x16x32_f16((a), (b), (c), 0, 0, 0)

constexpr int T_STEPS = 25;
constexpr int D = 128;
constexpr int NG = 384;   // 3*D
constexpr int BT = 64;    // batch rows per block
constexpr int SH = 136;   // f16 row stride: 272 B == 16 mod 128 -> uniform bank load for b128

typedef const __attribute__((address_space(1))) unsigned int guint;
typedef __attribute__((address_space(3))) unsigned int luint;

__device__ __forceinline__ void load_lds4(const float* g, float* l) {
    // one dword per lane, LDS dest = wave-uniform base + lane*4
    __builtin_amdgcn_global_load_lds((guint*)(uintptr_t)g, (luint*)l, 4, 0, 0);
}

__device__ __forceinline__ float sigm(float v) {
    return __builtin_amdgcn_rcpf(1.0f + __expf(-v));
}

__global__ __attribute__((amdgpu_flat_work_group_size(1024, 1024),
                          amdgpu_waves_per_eu(4, 4)))
void gru2_kernel(
    const float* __restrict__ x, const float* __restrict__ W1,
    const float* __restrict__ U1, const float* __restrict__ W2,
    const float* __restrict__ U2, const float* __restrict__ Wout,
    float* __restrict__ out) {
    __shared__ float    Xf[BT * D];      // raw x_t staging (DMA target), 32 KB
    __shared__ _Float16 Xh[2][BT * SH];  // x_t as f16, double-buffered (34.8 KB)
    __shared__ _Float16 H1[2][BT * SH];  // h1 state, double-buffered (34.8 KB)
    __shared__ _Float16 H2[2][BT * SH];  // h2 state, double-buffered (34.8 KB)

    const int tid = threadIdx.x;
    const int w = tid >> 6, lane = tid & 63, l15 = lane & 15, quad = lane >> 4;
    const int layer = w >> 3;       // 0: layer1 waves, 1: layer2 waves
    const int d0 = (w & 7) * 16;    // this wave's 16-col d-slice
    const int b0 = blockIdx.x * BT;

    // ---- one-time: this wave's [W;U] fragments as MFMA *A* operand ----
    // A-frag (16x16x32): lane holds A[m = l15][k = quad*8 + e]; A = weight^T,
    // i.e. element = Wgt[k][gate*128 + d0 + l15]. k-tiles 0..3 = W, 4..7 = U.
    half8 wg[3][8];
    {
        const float* Wp = layer ? W2 : W1;
        const float* Up = layer ? U2 : U1;
#pragma unroll
        for (int g = 0; g < 3; ++g) {
            const int c = g * 128 + d0 + l15;
#pragma unroll
            for (int kt = 0; kt < 8; ++kt) {
                const float* src = (kt < 4 ? Wp : Up) + (size_t)((kt & 3) * 32 + quad * 8) * NG + c;
                half8 f;
#pragma unroll
                for (int e = 0; e < 8; ++e) f[e] = (_Float16)src[(size_t)e * NG];
                wg[g][kt] = f;
            }
        }
    }
    // Pin all 24 fragments into AGPRs (96 AGPR) so they cannot be spilled.
#pragma unroll
    for (int g = 0; g < 3; ++g)
#pragma unroll
        for (int kt = 0; kt < 8; ++kt)
            asm volatile("" : "+a"(wg[g][kt]));

    // zero initial states: L1 reads H1[0] at iter 0; L2 reads H2[1] at iter 1
    for (int idx = tid; idx < BT * SH; idx += 1024) {
        H1[0][idx] = (_Float16)0.f;
        H2[1][idx] = (_Float16)0.f;
    }

    // prologue: DMA x(t=0) into Xf (128 lane-dword chunks, 8 per wave, linear)
#pragma unroll
    for (int r8 = 0; r8 < 8; ++r8) {
        const int idx = w * 8 + r8, row = idx >> 1, hf = (idx & 1) * 64;
        load_lds4(x + ((size_t)(b0 + row) * T_STEPS + 0) * D + hf + lane,
                  Xf + idx * 64);
    }
    __syncthreads();  // drains DMA (vmcnt(0) before s_barrier)

#pragma unroll 1
    for (int it = 0; it <= T_STEPS; ++it) {
        const int p = it & 1, q = p ^ 1;
        // ---- P1: convert Xf (f32, x(it)) -> Xh[p] (f16, padded) ----
        if (it < T_STEPS) {
#pragma unroll
            for (int c = 0; c < 2; ++c) {
                const int i0 = c * 4096 + tid * 4;     // dword index, 16 B/lane
                const float4 v = *(const float4*)(Xf + i0);
                const int row = i0 >> 7, col = i0 & 127;
                union { fp16x2 h2[2]; fp16x4 h4; } u;
                u.h2[0] = __builtin_amdgcn_cvt_pkrtz(v.x, v.y);
                u.h2[1] = __builtin_amdgcn_cvt_pkrtz(v.z, v.w);
                *(fp16x4*)(&Xh[p][row * SH + col]) = u.h4;
            }
        }
        __syncthreads();
        // ---- P2: DMA x(it+1) -> Xf; GRU compute ----
        if (it + 1 < T_STEPS) {
#pragma unroll
            for (int r8 = 0; r8 < 8; ++r8) {
                const int idx = w * 8 + r8, row = idx >> 1, hf = (idx & 1) * 64;
                load_lds4(x + ((size_t)(b0 + row) * T_STEPS + (it + 1)) * D + hf + lane,
                          Xf + idx * 64);
            }
        }
        const bool active = layer ? (it >= 1) : (it < T_STEPS);
        if (active) {
            const _Float16* Hst = layer ? H2[p] : H1[p];  // own state (h_prev)
            _Float16* Hout      = layer ? H2[q] : H1[q];  // own state dest
            const _Float16* Bin = layer ? H1[p] : Xh[p];  // layer input
#pragma unroll
            for (int nt = 0; nt < 4; ++nt) {
                const int bb = nt * 16 + l15;             // batch row (B-frag n=l15)
                const _Float16* bi = Bin + bb * SH + quad * 8;
                const _Float16* bs = Hst + bb * SH + quad * 8;
                f32x4 cz = {0.f, 0.f, 0.f, 0.f}, cr = {0.f, 0.f, 0.f, 0.f};
                f32x4 cxh = {0.f, 0.f, 0.f, 0.f}, cuh = {0.f, 0.f, 0.f, 0.f};
#pragma unroll
                for (int kt = 0; kt < 4; ++kt) {  // input part (W)
                    const half8 B = *(const half8*)(bi + kt * 32);
                    cz  = MFMA(wg[0][kt], B, cz);
                    cr  = MFMA(wg[1][kt], B, cr);
                    cxh = MFMA(wg[2][kt], B, cxh);
                }
#pragma unroll
                for (int kt = 0; kt < 4; ++kt) {  // state part (U)
                    const half8 B = *(const half8*)(bs + kt * 32);
                    cz  = MFMA(wg[0][4 + kt], B, cz);
                    cr  = MFMA(wg[1][4 + kt], B, cr);
                    cuh = MFMA(wg[2][4 + kt], B, cuh);
                }
                // C/D: col(N)=l15 -> batch bb; row(M)=quad*4+i2 -> d = d0+quad*4+i2
                const int hoff = bb * SH + d0 + quad * 4;
                const fp16x4 hp4 = *(const fp16x4*)(Hst + hoff);
                fp16x4 hn4;
#pragma unroll
                for (int i2 = 0; i2 < 4; ++i2) {
                    const float z = sigm(cz[i2]);
                    const float r = sigm(cr[i2]);
                    const float hh = cxh[i2] + r * cuh[i2];
                    hn4[i2] = (__fp16)(hh + z * ((float)hp4[i2] - hh));
                }
                *(fp16x4*)(Hout + hoff) = hn4;
            }
        }
        __syncthreads();
    }

    // ---- epilogue: out = h2(T-1) @ Wout; h2 is in H2[0]. Flipped operands:
    // A = Wout^T (regs), B = h2 (LDS). Waves 8-15, 16 out-cols each.
    if (layer) {
        half8 wO[4];
#pragma unroll
        for (int kt = 0; kt < 4; ++kt) {
            half8 f;
#pragma unroll
            for (int e = 0; e < 8; ++e)
                f[e] = (_Float16)Wout[(size_t)(kt * 32 + quad * 8 + e) * D + d0 + l15];
            wO[kt] = f;
        }
#pragma unroll
        for (int nt = 0; nt < 4; ++nt) {
            const _Float16* bp = H2[0] + (nt * 16 + l15) * SH + quad * 8;
            f32x4 acc = {0.f, 0.f, 0.f, 0.f};
#pragma unroll
            for (int kt = 0; kt < 4; ++kt)
                acc = MFMA(wO[kt], *(const half8*)(bp + kt * 32), acc);
            *(f32x4*)(out + (size_t)(b0 + nt * 16 + l15) * D + d0 + quad * 4) = acc;
        }
    }
}

extern "C" void kernel_launch(void* const* d_in, const int* in_sizes, int n_in,
                              void* d_out, int out_size, void* d_ws, size_t ws_size,
                              hipStream_t stream) {
    const float* x    = (const float*)d_in[0];
    const float* W1   = (const float*)d_in[1];
    const float* U1   = (const float*)d_in[2];
    const float* W2   = (const float*)d_in[3];
    const float* U2   = (const float*)d_in[4];
    const float* Wout = (const float*)d_in[5];
    gru2_kernel<<<dim3(16384 / BT), dim3(1024), 0, stream>>>(
        x, W1, U1, W2, U2, Wout, (float*)d_out);
}

// Round 7
// 484.256 us; speedup vs baseline: 1.9045x; 1.9045x over previous
//
#include <hip/hip_runtime.h>

// 2-layer GRU (reset_after, sigmoid gates, linear act, no bias) + Wout.
// B=16384, T=25, D=128. 256 blocks x 1024 threads (16 waves); block owns 64
// batch rows. Waves 0-7 = layer1 @ step it, waves 8-15 = layer2 @ step it-1.
// FLIPPED MFMA operands: weights = A operand (24 frags = 96 VGPRs), data = B
// operand streamed k-by-k from LDS. NO asm pinning (round 6 proved pinning
// forces per-use scratch re-reads -> 2.3 GB HBM). amdgpu_waves_per_eu(4,4)
// pins the register budget at 128/wave so the allocator cannot heuristically
// undershoot to 64 and spill the weights (round 5's failure mode).
// C/D = [d-col][batch]: h_prev re-read is 1 ds_read_b64, h write 1 b64/nt.
// x: f32 DMA (global_load_lds) double-buffer; layer-1 converts via pkrtz.

typedef _Float16 half8 __attribute__((ext_vector_type(8)));
typedef __fp16  fp16x2 __attribute__((ext_vector_type(2)));
typedef __fp16  fp16x4 __attribute__((ext_vector_type(4)));
typedef float    f32x4 __attribute__((ext_vector_type(4)));

#define MFMA(a, b, c) __builtin_amdgcn_mfma_f32_16x16x32_f16((a), (b), (c), 0, 0, 0)

constexpr int T_STEPS = 25;
constexpr int D = 128;
constexpr int NG = 384;   // 3*D
constexpr int BT = 64;    // batch rows per block
constexpr int SH = 136;   // f16 row stride: 272 B == 16 mod 128 -> benign 2-way on b128
constexpr int SX = 132;   // f32 row stride: 528 B == 16 mod 128 -> benign 2-way on b128

typedef const __attribute__((address_space(1))) unsigned int guint;
typedef __attribute__((address_space(3))) unsigned int luint;

__device__ __forceinline__ void load_lds4(const float* g, float* l) {
    // one dword per lane, LDS dest = wave-uniform base + lane*4
    __builtin_amdgcn_global_load_lds((guint*)(uintptr_t)g, (luint*)l, 4, 0, 0);
}

__device__ __forceinline__ float sigm(float v) {
    return __builtin_amdgcn_rcpf(1.0f + __expf(-v));
}

__device__ __forceinline__ half8 pkrtz8(const f32x4 v0, const f32x4 v1) {
    union { fp16x2 h2[4]; half8 h8; } u;
    u.h2[0] = __builtin_amdgcn_cvt_pkrtz(v0.x, v0.y);
    u.h2[1] = __builtin_amdgcn_cvt_pkrtz(v0.z, v0.w);
    u.h2[2] = __builtin_amdgcn_cvt_pkrtz(v1.x, v1.y);
    u.h2[3] = __builtin_amdgcn_cvt_pkrtz(v1.z, v1.w);
    return u.h8;
}

__global__ __attribute__((amdgpu_flat_work_group_size(1024, 1024),
                          amdgpu_waves_per_eu(4, 4)))
void gru2_kernel(
    const float* __restrict__ x, const float* __restrict__ W1,
    const float* __restrict__ U1, const float* __restrict__ W2,
    const float* __restrict__ U2, const float* __restrict__ Wout,
    float* __restrict__ out) {
    __shared__ float    X[2][BT * SX];   // x_t f32 staging, double-buffered (67.6 KB)
    __shared__ _Float16 H1[2][BT * SH];  // h1 state, double-buffered (34.8 KB)
    __shared__ _Float16 H2[2][BT * SH];  // h2 state, double-buffered (34.8 KB)

    const int tid = threadIdx.x;
    const int w = tid >> 6, lane = tid & 63, l15 = lane & 15, quad = lane >> 4;
    const int layer = w >> 3;       // 0: layer1 waves, 1: layer2 waves
    const int d0 = (w & 7) * 16;    // this wave's 16-col d-slice per gate
    const int b0 = blockIdx.x * BT;

    // ---- one-time: this wave's [W;U] fragments as MFMA *A* operand ----
    // A-frag (16x16x32): lane holds A[m = l15][k = quad*8 + e]; element =
    // Wgt[k][gate*128 + d0 + l15]. k-tiles 0..3 = W rows, 4..7 = U rows.
    half8 wg[3][8];
    {
        const float* Wp = layer ? W2 : W1;
        const float* Up = layer ? U2 : U1;
#pragma unroll
        for (int g = 0; g < 3; ++g) {
            const int c = g * 128 + d0 + l15;
#pragma unroll
            for (int kt = 0; kt < 8; ++kt) {
                const float* src = (kt < 4 ? Wp : Up) + (size_t)((kt & 3) * 32 + quad * 8) * NG + c;
                half8 f;
#pragma unroll
                for (int e = 0; e < 8; ++e) f[e] = (_Float16)src[(size_t)e * NG];
                wg[g][kt] = f;
            }
        }
    }

    // zero initial states: L1 reads H1[0] at iter 0; L2 reads H2[1] at iter 1
    for (int idx = tid; idx < BT * SH; idx += 1024) {
        H1[0][idx] = (_Float16)0.f;
        H2[1][idx] = (_Float16)0.f;
    }

    // prologue: DMA x(t=0) into X[0]: 128 lane-dword chunks, 8 per wave
#pragma unroll
    for (int r8 = 0; r8 < 8; ++r8) {
        const int idx = w * 8 + r8, row = idx >> 1, hf = (idx & 1) * 64;
        load_lds4(x + ((size_t)(b0 + row) * T_STEPS + 0) * D + hf + lane,
                  &X[0][row * SX + hf]);
    }
    __syncthreads();  // drains DMA (vmcnt(0) before s_barrier)

#pragma unroll 1
    for (int it = 0; it <= T_STEPS; ++it) {
        const int p = it & 1, q = p ^ 1;
        // issue DMA for x(it+1) -> X[q]; overlaps this iteration's compute.
        // X[q] readers finished at the barrier ending iter it-1.
        if (it + 1 < T_STEPS) {
#pragma unroll
            for (int r8 = 0; r8 < 8; ++r8) {
                const int idx = w * 8 + r8, row = idx >> 1, hf = (idx & 1) * 64;
                load_lds4(x + ((size_t)(b0 + row) * T_STEPS + (it + 1)) * D + hf + lane,
                          &X[q][row * SX + hf]);
            }
        }
        const bool active = layer ? (it >= 1) : (it < T_STEPS);
        if (active) {
            const _Float16* Hst = layer ? H2[p] : H1[p];  // own state (h_prev)
            _Float16* Hout      = layer ? H2[q] : H1[q];  // own state dest
            const _Float16* Hin = H1[p];                  // layer-2 input = h1
            const float* Xin    = X[p];                   // layer-1 input = x_t
#pragma unroll
            for (int nt = 0; nt < 4; ++nt) {
                const int bb = nt * 16 + l15;             // batch row (B-frag n)
                f32x4 cz = {0.f, 0.f, 0.f, 0.f}, cr = {0.f, 0.f, 0.f, 0.f};
                f32x4 cxh = {0.f, 0.f, 0.f, 0.f}, cuh = {0.f, 0.f, 0.f, 0.f};
                if (!layer) {
                    const float* bx = Xin + bb * SX + quad * 8;
#pragma unroll
                    for (int kt = 0; kt < 4; ++kt) {  // input part (W): x_t f32
                        const f32x4 v0 = *(const f32x4*)(bx + kt * 32);
                        const f32x4 v1 = *(const f32x4*)(bx + kt * 32 + 4);
                        const half8 B = pkrtz8(v0, v1);
                        cz  = MFMA(wg[0][kt], B, cz);
                        cr  = MFMA(wg[1][kt], B, cr);
                        cxh = MFMA(wg[2][kt], B, cxh);
                    }
                } else {
                    const _Float16* bi = Hin + bb * SH + quad * 8;
#pragma unroll
                    for (int kt = 0; kt < 4; ++kt) {  // input part (W): h1 f16
                        const half8 B = *(const half8*)(bi + kt * 32);
                        cz  = MFMA(wg[0][kt], B, cz);
                        cr  = MFMA(wg[1][kt], B, cr);
                        cxh = MFMA(wg[2][kt], B, cxh);
                    }
                }
                {
                    const _Float16* bs = Hst + bb * SH + quad * 8;
#pragma unroll
                    for (int kt = 0; kt < 4; ++kt) {  // state part (U): h_prev
                        const half8 B = *(const half8*)(bs + kt * 32);
                        cz  = MFMA(wg[0][4 + kt], B, cz);
                        cr  = MFMA(wg[1][4 + kt], B, cr);
                        cuh = MFMA(wg[2][4 + kt], B, cuh);
                    }
                }
                // C/D: col(N)=l15 -> batch bb; row(M)=quad*4+i2 -> d0+quad*4+i2
                const int hoff = bb * SH + d0 + quad * 4;
                const fp16x4 hp4 = *(const fp16x4*)(Hst + hoff);
                fp16x4 hn4;
#pragma unroll
                for (int i2 = 0; i2 < 4; ++i2) {
                    const float z = sigm(cz[i2]);
                    const float r = sigm(cr[i2]);
                    const float hh = cxh[i2] + r * cuh[i2];
                    hn4[i2] = (__fp16)(hh + z * ((float)hp4[i2] - hh));
                }
                *(fp16x4*)(Hout + hoff) = hn4;
            }
        }
        __syncthreads();
    }

    // ---- epilogue: out = h2(T-1) @ Wout; h2 is in H2[0]. Flipped operands:
    // A = Wout^T (regs), B = h2 (LDS). Waves 8-15, 16 out-cols each.
    if (layer) {
        half8 wO[4];
#pragma unroll
        for (int kt = 0; kt < 4; ++kt) {
            half8 f;
#pragma unroll
            for (int e = 0; e < 8; ++e)
                f[e] = (_Float16)Wout[(size_t)(kt * 32 + quad * 8 + e) * D + d0 + l15];
            wO[kt] = f;
        }
#pragma unroll
        for (int nt = 0; nt < 4; ++nt) {
            const _Float16* bp = H2[0] + (nt * 16 + l15) * SH + quad * 8;
            f32x4 acc = {0.f, 0.f, 0.f, 0.f};
#pragma unroll
            for (int kt = 0; kt < 4; ++kt)
                acc = MFMA(wO[kt], *(const half8*)(bp + kt * 32), acc);
            *(f32x4*)(out + (size_t)(b0 + nt * 16 + l15) * D + d0 + quad * 4) = acc;
        }
    }
}

extern "C" void kernel_launch(void* const* d_in, const int* in_sizes, int n_in,
                              void* d_out, int out_size, void* d_ws, size_t ws_size,
                              hipStream_t stream) {
    const float* x    = (const float*)d_in[0];
    const float* W1   = (const float*)d_in[1];
    const float* U1   = (const float*)d_in[2];
    const float* W2   = (const float*)d_in[3];
    const float* U2   = (const float*)d_in[4];
    const float* Wout = (const float*)d_in[5];
    gru2_kernel<<<dim3(16384 / BT), dim3(1024), 0, stream>>>(
        x, W1, U1, W2, U2, Wout, (float*)d_out);
}